// Round 5
// baseline (184.536 us; speedup 1.0000x reference)
//
#include <hip/hip_runtime.h>

#define BB 16
#define NN 1024
#define CC 64

typedef __attribute__((ext_vector_type(8))) short short8;
typedef __attribute__((ext_vector_type(4))) float f32x4;
typedef __attribute__((ext_vector_type(4))) int   i32x4;

__device__ __forceinline__ unsigned short bf16_rne(float f) {
    unsigned u = __float_as_uint(f);
    u += 0x7fffu + ((u >> 16) & 1u);
    return (unsigned short)(u >> 16);
}

// cubic through (e, w_edge[e]) for e=0..3 — exact branchless gather
#define WSEL_COEFFS(w_edge) \
    const float w0 = w_edge[0], w1 = w_edge[1], w2 = w_edge[2], w3 = w_edge[3]; \
    const float d1 = w1 - w0; \
    const float d2 = w2 - 2.f * w1 + w0; \
    const float d3 = w3 - 3.f * w2 + 3.f * w1 - w0; \
    const float c3 = d3 * (1.f / 6.f); \
    const float c2 = 0.5f * d2 - 0.5f * d3; \
    const float c1 = d1 - 0.5f * d2 + (1.f / 3.f) * d3; \
    const float c0 = w0;
#define WSEL(ev) __builtin_fmaf(__builtin_fmaf(__builtin_fmaf(c3, (float)(ev), c2), (float)(ev), c1), (float)(ev), c0)

// ---------------- Kernel 1: xw = x@W_rel -> bf16 swizzled (B-frag order);
//                  out = x@W_root + b_rel (fp32) ----------------
extern "C" __global__ __launch_bounds__(256)
void precompute(const float* __restrict__ x, const float* __restrict__ W_rel,
                const float* __restrict__ W_root, const float* __restrict__ b_rel,
                unsigned short* __restrict__ xw_sw, float* __restrict__ out)
{
    __shared__ float wrel_s[64 * 64];
    __shared__ float wroot_s[64 * 64];
    __shared__ float x_s[16 * 68];

    const int t = threadIdx.x;
    #pragma unroll
    for (int k = 0; k < 4; ++k) {
        int i4 = t + 256 * k;
        ((float4*)wrel_s)[i4]  = ((const float4*)W_rel)[i4];
        ((float4*)wroot_s)[i4] = ((const float4*)W_root)[i4];
    }
    const int row0 = blockIdx.x * 16;
    {
        int r = t >> 4, c4 = t & 15;
        *(float4*)(x_s + r * 68 + c4 * 4) = ((const float4*)(x + (size_t)(row0 + r) * CC))[c4];
    }
    __syncthreads();

    const int c4 = t & 15;
    const int r  = t >> 4;
    float aw0 = 0.f, aw1 = 0.f, aw2 = 0.f, aw3 = 0.f;
    float ar0 = 0.f, ar1 = 0.f, ar2 = 0.f, ar3 = 0.f;
    const float* xrow = x_s + r * 68;
    #pragma unroll 8
    for (int k = 0; k < 64; ++k) {
        float xv = xrow[k];
        float4 wv = ((const float4*)(wrel_s  + k * 64))[c4];
        float4 rv = ((const float4*)(wroot_s + k * 64))[c4];
        aw0 += xv * wv.x; aw1 += xv * wv.y; aw2 += xv * wv.z; aw3 += xv * wv.w;
        ar0 += xv * rv.x; ar1 += xv * rv.y; ar2 += xv * rv.z; ar3 += xv * rv.w;
    }

    const int row_g = row0 + r;
    {
        const float4 bv = ((const float4*)b_rel)[c4];
        ((float4*)out)[(size_t)row_g * 16 + c4] =
            make_float4(ar0 + bv.x, ar1 + bv.y, ar2 + bv.z, ar3 + bv.w);
    }
    {
        const int b = row_g >> 10;
        const int k = row_g & 1023;
        const int kb = k >> 5;
        const int qk = (k >> 3) & 3;
        const int j  = k & 7;
        const int c  = 4 * c4;
        const int n0 = c >> 4;
        const int n  = c & 15;
        size_t off = ((size_t)b << 16) + (size_t)((kb * 4 + n0) << 9)
                   + (size_t)((n + (qk << 4)) << 3) + j;
        xw_sw[off]      = bf16_rne(aw0);
        xw_sw[off + 8]  = bf16_rne(aw1);
        xw_sw[off + 16] = bf16_rne(aw2);
        xw_sw[off + 24] = bf16_rne(aw3);
    }
}

// ---------------- Kernel 2a: pack adjw = bf16(adj * wsel(ea)), linear ------
// Maximally fill-like pure stream: grid-stride, no LDS, no barriers, no MFMA.
// 524288 threads, each handles 8 f32x4-quads (phase-dense: quad = j*S + g,
// so every wave instruction reads 1KB contiguous). nt loads (zero reuse);
// NORMAL cached stores (gnn_lite reads adjw right back from L2/L3).
// Clean read-BW experiment: if this caps at ~2.6 TB/s too, ceiling is real.
extern "C" __global__ __launch_bounds__(256)
void pack(const float* __restrict__ adj, const int* __restrict__ ea,
          const float* __restrict__ w_edge, uint2* __restrict__ adjw)
{
    const int g = blockIdx.x * 256 + threadIdx.x;   // 0 .. 524287
    const int S = 2048 * 256;                       // phase stride (threads)

    WSEL_COEFFS(w_edge);

    const f32x4* A4 = (const f32x4*)adj;
    const i32x4* E4 = (const i32x4*)ea;

    f32x4 a[4]; i32x4 e[4];
    #pragma unroll
    for (int j = 0; j < 4; ++j) {
        a[j] = __builtin_nontemporal_load(&A4[(size_t)j * S + g]);
        e[j] = __builtin_nontemporal_load(&E4[(size_t)j * S + g]);
    }

    #pragma unroll
    for (int j = 0; j < 8; ++j) {
        f32x4 av = a[j & 3];
        i32x4 ev = e[j & 3];
        if (j < 4) {
            a[j & 3] = __builtin_nontemporal_load(&A4[(size_t)(j + 4) * S + g]);
            e[j & 3] = __builtin_nontemporal_load(&E4[(size_t)(j + 4) * S + g]);
        }
        float p0 = av[0] * WSEL(ev[0]);
        float p1 = av[1] * WSEL(ev[1]);
        float p2 = av[2] * WSEL(ev[2]);
        float p3 = av[3] * WSEL(ev[3]);
        unsigned u0 = __builtin_amdgcn_perm(__float_as_uint(p1), __float_as_uint(p0), 0x07060302u);
        unsigned u1 = __builtin_amdgcn_perm(__float_as_uint(p3), __float_as_uint(p2), 0x07060302u);
        adjw[(size_t)j * S + g] = make_uint2(u0, u1);
    }
}

// ---------------- Kernel 2b: out += adjw @ xw  (bf16 MFMA, no LDS) ---------
// A-frags loaded DIRECTLY from linear adjw (L2/L3-hot, just written by pack):
// lane (m,q) reads 16B at row (row0+m), k = kb*32 + q*8. xw B-frags from
// B-frag-order global (L2-resident). 4 waves = 4 col-quarters.
// Exclusive 16-row ownership -> plain RMW, no atomics. No LDS, no barriers.
extern "C" __global__ __launch_bounds__(256)
void gnn_lite(const unsigned short* __restrict__ adjw,
              const unsigned short* __restrict__ xw_sw,
              float* __restrict__ out)
{
    const int t     = threadIdx.x;
    const int wn    = t >> 6;           // 16-col quarter
    const int lane  = t & 63;
    const int m     = lane & 15;
    const int q     = lane >> 4;
    const int mtile = blockIdx.x & 63;
    const int b     = blockIdx.x >> 6;
    const int row0  = mtile << 4;

    const unsigned short* ap = adjw + ((size_t)b << 20)
                             + ((size_t)(row0 + m) << 10) + (q << 3);
    const unsigned short* xwb = xw_sw + ((size_t)b << 16)
                              + ((size_t)wn << 9) + ((size_t)lane << 3);

    f32x4 acc = {0.f, 0.f, 0.f, 0.f};

    #pragma unroll
    for (int kb = 0; kb < 32; ++kb) {
        short8 af = *(const short8*)(ap + (kb << 5));
        short8 bf = *(const short8*)(xwb + ((size_t)kb << 11));
        acc = __builtin_amdgcn_mfma_f32_16x16x32_bf16(af, bf, acc, 0, 0, 0);
    }

    float* ob = out + ((((size_t)b << 10) + row0 + (q << 2)) << 6) + (wn << 4) + m;
    #pragma unroll
    for (int rg = 0; rg < 4; ++rg) {
        ob[rg * 64] += acc[rg];
    }
}

// ---------------- Fallback fused kernel (v4, 164.9us config) ---------------
// Used when ws_size can't hold adjw (36 MiB). Only needs xw_sw (2 MiB).
extern "C" __global__ __launch_bounds__(256, 4)
void gnn_mfma(const float* __restrict__ adj, const int* __restrict__ ea,
              const float* __restrict__ w_edge,
              const unsigned short* __restrict__ xw_sw,
              float* __restrict__ out)
{
    __shared__ __align__(16) char lds[32768];

    const int t     = threadIdx.x;
    const int mtile = blockIdx.x & 63;
    const int b     = blockIdx.x >> 6;
    const int row0  = mtile << 4;

    WSEL_COEFFS(w_edge);

    const size_t gbase = ((size_t)b << 20) + ((size_t)row0 << 10);
    const f32x4* A4 = (const f32x4*)(adj + gbase);
    const i32x4* E4 = (const i32x4*)(ea + gbase);

    const int kb_t   = t >> 3;
    const int q_t    = (t >> 1) & 3;
    const int X_t    = ((kb_t & 3) << 2) | q_t;
    const int wbase  = (kb_t << 10) + (q_t << 8) + ((t & 1) << 3);

    f32x4 aa[8]; i32x4 ee[8];
    #pragma unroll
    for (int d = 0; d < 8; ++d) {
        aa[d] = __builtin_nontemporal_load(&A4[d * 256 + t]);
        ee[d] = __builtin_nontemporal_load(&E4[d * 256 + t]);
    }

    #pragma unroll
    for (int i = 0; i < 16; ++i) {
        f32x4 av = aa[i & 7];
        i32x4 ev = ee[i & 7];
        if (i < 8) {
            aa[i & 7] = __builtin_nontemporal_load(&A4[(i + 8) * 256 + t]);
            ee[i & 7] = __builtin_nontemporal_load(&E4[(i + 8) * 256 + t]);
        }
        float p0 = av[0] * WSEL(ev[0]);
        float p1 = av[1] * WSEL(ev[1]);
        float p2 = av[2] * WSEL(ev[2]);
        float p3 = av[3] * WSEL(ev[3]);
        unsigned u0 = __builtin_amdgcn_perm(__float_as_uint(p1), __float_as_uint(p0), 0x07060302u);
        unsigned u1 = __builtin_amdgcn_perm(__float_as_uint(p3), __float_as_uint(p2), 0x07060302u);
        const int m = i;
        const int addr = wbase + ((m ^ X_t) << 4);
        *(uint2*)(lds + addr) = make_uint2(u0, u1);
    }
    __syncthreads();

    const int wn   = t >> 6;
    const int lane = t & 63;
    const int m    = lane & 15;
    const int q    = lane >> 4;

    const unsigned short* xwb = xw_sw + ((size_t)b << 16)
                              + ((size_t)wn << 9) + ((size_t)lane << 3);
    const char* abase = lds + (q << 8);

    f32x4 acc0 = {0.f, 0.f, 0.f, 0.f};

    #pragma unroll
    for (int kb = 0; kb < 32; ++kb) {
        const int X = ((kb & 3) << 2) | q;
        short8 af = *(const short8*)(abase + (kb << 10) + ((m ^ X) << 4));
        short8 bf = *(const short8*)(xwb + ((size_t)kb << 11));
        acc0 = __builtin_amdgcn_mfma_f32_16x16x32_bf16(af, bf, acc0, 0, 0, 0);
    }

    float* ob = out + ((((size_t)b << 10) + row0 + (q << 2)) << 6) + (wn << 4) + m;
    #pragma unroll
    for (int rg = 0; rg < 4; ++rg) {
        ob[rg * 64] += acc0[rg];
    }
}

extern "C" void kernel_launch(void* const* d_in, const int* in_sizes, int n_in,
                              void* d_out, int out_size, void* d_ws, size_t ws_size,
                              hipStream_t stream) {
    const float* x      = (const float*)d_in[0];
    const float* adj    = (const float*)d_in[1];
    const int*   ea     = (const int*)  d_in[2];
    const float* W_rel  = (const float*)d_in[3];
    const float* b_rel  = (const float*)d_in[4];
    const float* W_root = (const float*)d_in[5];
    const float* w_edge = (const float*)d_in[6];
    float* out = (float*)d_out;

    unsigned short* xw_sw = (unsigned short*)d_ws;               // 2 MiB @ 0

    precompute<<<BB * NN / 16, 256, 0, stream>>>(x, W_rel, W_root, b_rel, xw_sw, out);

    const size_t need = ((size_t)1 << 22) + ((size_t)32 << 20);  // 4 MiB + 32 MiB
    if (ws_size >= need) {
        uint2* adjw = (uint2*)((char*)d_ws + ((size_t)1 << 22)); // 32 MiB @ +4 MiB
        pack<<<2048, 256, 0, stream>>>(adj, ea, w_edge, adjw);
        gnn_lite<<<BB * (NN / 16), 256, 0, stream>>>((const unsigned short*)adjw, xw_sw, out);
    } else {
        gnn_mfma<<<BB * (NN / 16), 256, 0, stream>>>(adj, ea, w_edge, xw_sw, out);
    }
}

// Round 6
// 170.214 us; speedup vs baseline: 1.0841x; 1.0841x over previous
//
#include <hip/hip_runtime.h>

#define BB 16
#define NN 1024
#define CC 64

typedef __attribute__((ext_vector_type(8))) short short8;
typedef __attribute__((ext_vector_type(4))) float f32x4;
typedef __attribute__((ext_vector_type(4))) int   i32x4;

__device__ __forceinline__ unsigned short bf16_rne(float f) {
    unsigned u = __float_as_uint(f);
    u += 0x7fffu + ((u >> 16) & 1u);
    return (unsigned short)(u >> 16);
}

// cubic through (e, w_edge[e]) for e=0..3 — exact branchless gather
#define WSEL_COEFFS(w_edge) \
    const float w0 = w_edge[0], w1 = w_edge[1], w2 = w_edge[2], w3 = w_edge[3]; \
    const float d1 = w1 - w0; \
    const float d2 = w2 - 2.f * w1 + w0; \
    const float d3 = w3 - 3.f * w2 + 3.f * w1 - w0; \
    const float c3 = d3 * (1.f / 6.f); \
    const float c2 = 0.5f * d2 - 0.5f * d3; \
    const float c1 = d1 - 0.5f * d2 + (1.f / 3.f) * d3; \
    const float c0 = w0;
#define WSEL(ev) __builtin_fmaf(__builtin_fmaf(__builtin_fmaf(c3, (float)(ev), c2), (float)(ev), c1), (float)(ev), c0)

// ---------------- Kernel 1: xw = x@W_rel -> bf16 swizzled (B-frag order);
//                  out = x@W_root + b_rel (fp32) ----------------
extern "C" __global__ __launch_bounds__(256)
void precompute(const float* __restrict__ x, const float* __restrict__ W_rel,
                const float* __restrict__ W_root, const float* __restrict__ b_rel,
                unsigned short* __restrict__ xw_sw, float* __restrict__ out)
{
    __shared__ float wrel_s[64 * 64];
    __shared__ float wroot_s[64 * 64];
    __shared__ float x_s[16 * 68];

    const int t = threadIdx.x;
    #pragma unroll
    for (int k = 0; k < 4; ++k) {
        int i4 = t + 256 * k;
        ((float4*)wrel_s)[i4]  = ((const float4*)W_rel)[i4];
        ((float4*)wroot_s)[i4] = ((const float4*)W_root)[i4];
    }
    const int row0 = blockIdx.x * 16;
    {
        int r = t >> 4, c4 = t & 15;
        *(float4*)(x_s + r * 68 + c4 * 4) = ((const float4*)(x + (size_t)(row0 + r) * CC))[c4];
    }
    __syncthreads();

    const int c4 = t & 15;
    const int r  = t >> 4;
    float aw0 = 0.f, aw1 = 0.f, aw2 = 0.f, aw3 = 0.f;
    float ar0 = 0.f, ar1 = 0.f, ar2 = 0.f, ar3 = 0.f;
    const float* xrow = x_s + r * 68;
    #pragma unroll 8
    for (int k = 0; k < 64; ++k) {
        float xv = xrow[k];
        float4 wv = ((const float4*)(wrel_s  + k * 64))[c4];
        float4 rv = ((const float4*)(wroot_s + k * 64))[c4];
        aw0 += xv * wv.x; aw1 += xv * wv.y; aw2 += xv * wv.z; aw3 += xv * wv.w;
        ar0 += xv * rv.x; ar1 += xv * rv.y; ar2 += xv * rv.z; ar3 += xv * rv.w;
    }

    const int row_g = row0 + r;
    {
        const float4 bv = ((const float4*)b_rel)[c4];
        ((float4*)out)[(size_t)row_g * 16 + c4] =
            make_float4(ar0 + bv.x, ar1 + bv.y, ar2 + bv.z, ar3 + bv.w);
    }
    {
        const int b = row_g >> 10;
        const int k = row_g & 1023;
        const int kb = k >> 5;
        const int qk = (k >> 3) & 3;
        const int j  = k & 7;
        const int c  = 4 * c4;
        const int n0 = c >> 4;
        const int n  = c & 15;
        size_t off = ((size_t)b << 16) + (size_t)((kb * 4 + n0) << 9)
                   + (size_t)((n + (qk << 4)) << 3) + j;
        xw_sw[off]      = bf16_rne(aw0);
        xw_sw[off + 8]  = bf16_rne(aw1);
        xw_sw[off + 16] = bf16_rne(aw2);
        xw_sw[off + 24] = bf16_rne(aw3);
    }
}

// ---------------- Kernel 2: out += (adj .* w_edge[ea]) @ xw  (bf16 MFMA) ----
// v6 = v4's fused structure with the one untested lever flipped:
//   - NORMAL (cached) loads for adj/ea instead of nontemporal. Rounds 0-2
//     showed FETCH_SIZE = 74 MB < 134 MB logical: the harness restore fills
//     leave ~60 MB of adj/ea L3-resident each iteration. nt loads bypass L3
//     and pay full HBM; normal loads harvest the hits. v4's other lever
//     (16-row blocks, high streaming occupancy) is kept — if occupancy, not
//     nt, was v4's real gain, this config takes both benefits.
//   - __launch_bounds__(256,5): 5 blocks/CU (5 x 32 KB LDS = 160 KB exactly).
// Phase A: thread t owns k in [4t,4t+4) of every row; each wave instruction
//   reads 1KB contiguous; 8-row-deep register pipeline; convert to bf16
//   adj*wsel(ea), write A-frags to LDS with XOR swizzle (m ^= ((kb&3)<<2)|q).
// Phase B: 32 MFMA k-steps; A-frags from LDS (conflict-free b128), xw B-frags
//   from global (2MB, L2-resident). Exclusive 16-row ownership -> plain RMW.
extern "C" __global__ __launch_bounds__(256, 5)
void gnn_mfma(const float* __restrict__ adj, const int* __restrict__ ea,
              const float* __restrict__ w_edge,
              const unsigned short* __restrict__ xw_sw,
              float* __restrict__ out)
{
    __shared__ __align__(16) char lds[32768];

    const int t     = threadIdx.x;
    const int mtile = blockIdx.x & 63;
    const int b     = blockIdx.x >> 6;
    const int row0  = mtile << 4;

    WSEL_COEFFS(w_edge);

    // ---------------- Phase A: cached stream + convert + swizzled LDS write --
    const size_t gbase = ((size_t)b << 20) + ((size_t)row0 << 10);
    const f32x4* A4 = (const f32x4*)(adj + gbase);
    const i32x4* E4 = (const i32x4*)(ea + gbase);

    const int kb_t   = t >> 3;
    const int q_t    = (t >> 1) & 3;
    const int X_t    = ((kb_t & 3) << 2) | q_t;
    const int wbase  = (kb_t << 10) + (q_t << 8) + ((t & 1) << 3);

    f32x4 aa[8]; i32x4 ee[8];
    #pragma unroll
    for (int d = 0; d < 8; ++d) {
        aa[d] = A4[d * 256 + t];
        ee[d] = E4[d * 256 + t];
    }

    #pragma unroll
    for (int i = 0; i < 16; ++i) {
        f32x4 av = aa[i & 7];
        i32x4 ev = ee[i & 7];
        if (i < 8) {                        // prefetch row i+8 (compile-time guard)
            aa[i & 7] = A4[(i + 8) * 256 + t];
            ee[i & 7] = E4[(i + 8) * 256 + t];
        }
        float p0 = av[0] * WSEL(ev[0]);
        float p1 = av[1] * WSEL(ev[1]);
        float p2 = av[2] * WSEL(ev[2]);
        float p3 = av[3] * WSEL(ev[3]);
        unsigned u0 = __builtin_amdgcn_perm(__float_as_uint(p1), __float_as_uint(p0), 0x07060302u);
        unsigned u1 = __builtin_amdgcn_perm(__float_as_uint(p3), __float_as_uint(p2), 0x07060302u);
        const int m = i;                    // row within 16-row tile
        const int addr = wbase + ((m ^ X_t) << 4);
        *(uint2*)(lds + addr) = make_uint2(u0, u1);
    }
    __syncthreads();

    // ---------------- Phase B: MFMA from LDS A-frags + global xw B-frags ------
    const int wn   = t >> 6;            // 16-col quarter
    const int lane = t & 63;
    const int m    = lane & 15;
    const int q    = lane >> 4;

    const unsigned short* xwb = xw_sw + ((size_t)b << 16)
                              + ((size_t)wn << 9) + ((size_t)lane << 3);
    const char* abase = lds + (q << 8);

    f32x4 acc0 = {0.f, 0.f, 0.f, 0.f};

    #pragma unroll
    for (int kb = 0; kb < 32; ++kb) {
        const int X = ((kb & 3) << 2) | q;
        short8 af = *(const short8*)(abase + (kb << 10) + ((m ^ X) << 4));
        short8 bf = *(const short8*)(xwb + ((size_t)kb << 11));
        acc0 = __builtin_amdgcn_mfma_f32_16x16x32_bf16(af, bf, acc0, 0, 0, 0);
    }

    // ---------------- epilogue: exclusive rows -> plain RMW, no atomics ------
    float* ob = out + ((((size_t)b << 10) + row0 + (q << 2)) << 6) + (wn << 4) + m;
    #pragma unroll
    for (int rg = 0; rg < 4; ++rg) {
        ob[rg * 64] += acc0[rg];
    }
}

extern "C" void kernel_launch(void* const* d_in, const int* in_sizes, int n_in,
                              void* d_out, int out_size, void* d_ws, size_t ws_size,
                              hipStream_t stream) {
    const float* x      = (const float*)d_in[0];
    const float* adj    = (const float*)d_in[1];
    const int*   ea     = (const int*)  d_in[2];
    const float* W_rel  = (const float*)d_in[3];
    const float* b_rel  = (const float*)d_in[4];
    const float* W_root = (const float*)d_in[5];
    const float* w_edge = (const float*)d_in[6];
    float* out = (float*)d_out;

    unsigned short* xw_sw = (unsigned short*)d_ws;   // B*N*C bf16 = 2 MiB

    precompute<<<BB * NN / 16, 256, 0, stream>>>(x, W_rel, W_root, b_rel, xw_sw, out);
    gnn_mfma<<<BB * (NN / 16), 256, 0, stream>>>(adj, ea, w_edge, xw_sw, out);
}

// Round 7
// 165.045 us; speedup vs baseline: 1.1181x; 1.0313x over previous
//
#include <hip/hip_runtime.h>

#define BB 16
#define NN 1024
#define CC 64

typedef __attribute__((ext_vector_type(8))) short short8;
typedef __attribute__((ext_vector_type(4))) float f32x4;
typedef __attribute__((ext_vector_type(4))) int   i32x4;

__device__ __forceinline__ unsigned short bf16_rne(float f) {
    unsigned u = __float_as_uint(f);
    u += 0x7fffu + ((u >> 16) & 1u);
    return (unsigned short)(u >> 16);
}

// cubic through (e, w_edge[e]) for e=0..3 — exact branchless gather
#define WSEL_COEFFS(w_edge) \
    const float w0 = w_edge[0], w1 = w_edge[1], w2 = w_edge[2], w3 = w_edge[3]; \
    const float d1 = w1 - w0; \
    const float d2 = w2 - 2.f * w1 + w0; \
    const float d3 = w3 - 3.f * w2 + 3.f * w1 - w0; \
    const float c3 = d3 * (1.f / 6.f); \
    const float c2 = 0.5f * d2 - 0.5f * d3; \
    const float c1 = d1 - 0.5f * d2 + (1.f / 3.f) * d3; \
    const float c0 = w0;
#define WSEL(ev) __builtin_fmaf(__builtin_fmaf(__builtin_fmaf(c3, (float)(ev), c2), (float)(ev), c1), (float)(ev), c0)

// ---------------- Kernel 1: xw = x@W_rel -> bf16 swizzled (B-frag order);
//                  out = x@W_root + b_rel (fp32) ----------------
extern "C" __global__ __launch_bounds__(256)
void precompute(const float* __restrict__ x, const float* __restrict__ W_rel,
                const float* __restrict__ W_root, const float* __restrict__ b_rel,
                unsigned short* __restrict__ xw_sw, float* __restrict__ out)
{
    __shared__ float wrel_s[64 * 64];
    __shared__ float wroot_s[64 * 64];
    __shared__ float x_s[16 * 68];

    const int t = threadIdx.x;
    #pragma unroll
    for (int k = 0; k < 4; ++k) {
        int i4 = t + 256 * k;
        ((float4*)wrel_s)[i4]  = ((const float4*)W_rel)[i4];
        ((float4*)wroot_s)[i4] = ((const float4*)W_root)[i4];
    }
    const int row0 = blockIdx.x * 16;
    {
        int r = t >> 4, c4 = t & 15;
        *(float4*)(x_s + r * 68 + c4 * 4) = ((const float4*)(x + (size_t)(row0 + r) * CC))[c4];
    }
    __syncthreads();

    const int c4 = t & 15;
    const int r  = t >> 4;
    float aw0 = 0.f, aw1 = 0.f, aw2 = 0.f, aw3 = 0.f;
    float ar0 = 0.f, ar1 = 0.f, ar2 = 0.f, ar3 = 0.f;
    const float* xrow = x_s + r * 68;
    #pragma unroll 8
    for (int k = 0; k < 64; ++k) {
        float xv = xrow[k];
        float4 wv = ((const float4*)(wrel_s  + k * 64))[c4];
        float4 rv = ((const float4*)(wroot_s + k * 64))[c4];
        aw0 += xv * wv.x; aw1 += xv * wv.y; aw2 += xv * wv.z; aw3 += xv * wv.w;
        ar0 += xv * rv.x; ar1 += xv * rv.y; ar2 += xv * rv.z; ar3 += xv * rv.w;
    }

    const int row_g = row0 + r;
    {
        const float4 bv = ((const float4*)b_rel)[c4];
        ((float4*)out)[(size_t)row_g * 16 + c4] =
            make_float4(ar0 + bv.x, ar1 + bv.y, ar2 + bv.z, ar3 + bv.w);
    }
    {
        const int b = row_g >> 10;
        const int k = row_g & 1023;
        const int kb = k >> 5;
        const int qk = (k >> 3) & 3;
        const int j  = k & 7;
        const int c  = 4 * c4;
        const int n0 = c >> 4;
        const int n  = c & 15;
        size_t off = ((size_t)b << 16) + (size_t)((kb * 4 + n0) << 9)
                   + (size_t)((n + (qk << 4)) << 3) + j;
        xw_sw[off]      = bf16_rne(aw0);
        xw_sw[off + 8]  = bf16_rne(aw1);
        xw_sw[off + 16] = bf16_rne(aw2);
        xw_sw[off + 24] = bf16_rne(aw3);
    }
}

// ---------------- Kernel 2: out += (adj .* w_edge[ea]) @ xw  (bf16 MFMA) ----
// v7 = v4 verbatim (best verified config, 164.9us total). Factorial over
// {load policy} x {tile/occupancy} proved nontemporal is the real lever:
//   normal loads harvest ~58MB L3-resident adj/ea but the L3-hit service
//   path caps at ~1.7 TB/s (v3: 52us, v6: 47-49us); nt bypasses L3 and
//   streams at ~3.6-4 TB/s (v4: gnn ~37-41us). 16-row blocks, 4 blk/CU.
// Phase A: thread t owns k in [4t,4t+4) of every row; each wave instruction
//   reads 1KB contiguous; 8-row-deep register pipeline; convert to bf16
//   adj*wsel(ea), write A-frags to LDS with XOR swizzle (m ^= ((kb&3)<<2)|q).
// Phase B: 32 MFMA k-steps; A-frags from LDS (conflict-free b128), xw B-frags
//   from global (2MB, L2-resident). Exclusive 16-row ownership -> plain RMW.
extern "C" __global__ __launch_bounds__(256, 4)
void gnn_mfma(const float* __restrict__ adj, const int* __restrict__ ea,
              const float* __restrict__ w_edge,
              const unsigned short* __restrict__ xw_sw,
              float* __restrict__ out)
{
    __shared__ __align__(16) char lds[32768];

    const int t     = threadIdx.x;
    const int mtile = blockIdx.x & 63;
    const int b     = blockIdx.x >> 6;
    const int row0  = mtile << 4;

    WSEL_COEFFS(w_edge);

    // ---------------- Phase A: nt-stream + convert + swizzled LDS-frag write --
    const size_t gbase = ((size_t)b << 20) + ((size_t)row0 << 10);
    const f32x4* A4 = (const f32x4*)(adj + gbase);
    const i32x4* E4 = (const i32x4*)(ea + gbase);

    const int kb_t   = t >> 3;
    const int q_t    = (t >> 1) & 3;
    const int X_t    = ((kb_t & 3) << 2) | q_t;
    const int wbase  = (kb_t << 10) + (q_t << 8) + ((t & 1) << 3);

    f32x4 aa[8]; i32x4 ee[8];
    #pragma unroll
    for (int d = 0; d < 8; ++d) {
        aa[d] = __builtin_nontemporal_load(&A4[d * 256 + t]);
        ee[d] = __builtin_nontemporal_load(&E4[d * 256 + t]);
    }

    #pragma unroll
    for (int i = 0; i < 16; ++i) {
        f32x4 av = aa[i & 7];
        i32x4 ev = ee[i & 7];
        if (i < 8) {                        // prefetch row i+8 (compile-time guard)
            aa[i & 7] = __builtin_nontemporal_load(&A4[(i + 8) * 256 + t]);
            ee[i & 7] = __builtin_nontemporal_load(&E4[(i + 8) * 256 + t]);
        }
        float p0 = av[0] * WSEL(ev[0]);
        float p1 = av[1] * WSEL(ev[1]);
        float p2 = av[2] * WSEL(ev[2]);
        float p3 = av[3] * WSEL(ev[3]);
        unsigned u0 = __builtin_amdgcn_perm(__float_as_uint(p1), __float_as_uint(p0), 0x07060302u);
        unsigned u1 = __builtin_amdgcn_perm(__float_as_uint(p3), __float_as_uint(p2), 0x07060302u);
        const int m = i;                    // row within 16-row tile
        const int addr = wbase + ((m ^ X_t) << 4);
        *(uint2*)(lds + addr) = make_uint2(u0, u1);
    }
    __syncthreads();

    // ---------------- Phase B: MFMA from LDS A-frags + global xw B-frags ------
    const int wn   = t >> 6;            // 16-col quarter
    const int lane = t & 63;
    const int m    = lane & 15;
    const int q    = lane >> 4;

    const unsigned short* xwb = xw_sw + ((size_t)b << 16)
                              + ((size_t)wn << 9) + ((size_t)lane << 3);
    const char* abase = lds + (q << 8);

    f32x4 acc0 = {0.f, 0.f, 0.f, 0.f};

    #pragma unroll
    for (int kb = 0; kb < 32; ++kb) {
        const int X = ((kb & 3) << 2) | q;
        short8 af = *(const short8*)(abase + (kb << 10) + ((m ^ X) << 4));
        short8 bf = *(const short8*)(xwb + ((size_t)kb << 11));
        acc0 = __builtin_amdgcn_mfma_f32_16x16x32_bf16(af, bf, acc0, 0, 0, 0);
    }

    // ---------------- epilogue: exclusive rows -> plain RMW, no atomics ------
    float* ob = out + ((((size_t)b << 10) + row0 + (q << 2)) << 6) + (wn << 4) + m;
    #pragma unroll
    for (int rg = 0; rg < 4; ++rg) {
        ob[rg * 64] += acc0[rg];
    }
}

extern "C" void kernel_launch(void* const* d_in, const int* in_sizes, int n_in,
                              void* d_out, int out_size, void* d_ws, size_t ws_size,
                              hipStream_t stream) {
    const float* x      = (const float*)d_in[0];
    const float* adj    = (const float*)d_in[1];
    const int*   ea     = (const int*)  d_in[2];
    const float* W_rel  = (const float*)d_in[3];
    const float* b_rel  = (const float*)d_in[4];
    const float* W_root = (const float*)d_in[5];
    const float* w_edge = (const float*)d_in[6];
    float* out = (float*)d_out;

    unsigned short* xw_sw = (unsigned short*)d_ws;   // B*N*C bf16 = 2 MiB

    precompute<<<BB * NN / 16, 256, 0, stream>>>(x, W_rel, W_root, b_rel, xw_sw, out);
    gnn_mfma<<<BB * (NN / 16), 256, 0, stream>>>(adj, ea, w_edge, xw_sw, out);
}